// Round 3
// baseline (1513.408 us; speedup 1.0000x reference)
//
#include <hip/hip_runtime.h>

#define B_ 8
#define N_ 384
#define K_ 383
#define NT_ 4

__device__ __forceinline__ float fast_tanh(float x) {
    // tanh(x) = 1 - 2/(exp(2x)+1); saturates correctly for |x| large.
    float e = __expf(2.0f * x);
    return 1.0f - 2.0f / (e + 1.0f);
}

__global__ __launch_bounds__(512, 1)
void feat_kernel(const float* __restrict__ coords,
                 const int*   __restrict__ types,
                 const float* __restrict__ W0, const float* __restrict__ b0,
                 const float* __restrict__ W1, const float* __restrict__ b1,
                 const float* __restrict__ W2, const float* __restrict__ b2,
                 float* __restrict__ out)
{
    // stride 101 (odd) -> conflict-free column access across lanes
    __shared__ float G[384 * 101];     // 155,136 B
    __shared__ float Al[384 * 3];      //   4,608 B
    __shared__ int   ksort[384];       //   1,536 B
    __shared__ float Sl[304];          //   1,216 B
    __shared__ int   cnt[4], woff[4];  //      32 B   -> total ~158.7 KiB

    const int t  = threadIdx.x;
    const int bn = blockIdx.x;
    const int b  = bn / N_;
    const int n  = bn % N_;

    const int tn = types[n];

    if (t < 4) cnt[t] = 0;
    __syncthreads();

    int myty = -1;
    if (t < K_) {
        int j = t + (t >= n);
        myty = types[j];
        atomicAdd(&cnt[myty], 1);
    }
    __syncthreads();
    if (t == 0) {
        int r = 0;
        for (int q = 0; q < 4; ++q) { woff[q] = r; r += cnt[q]; }
    }
    __syncthreads();
    if (t < K_) {
        int slot = atomicAdd(&woff[myty], 1);
        ksort[slot] = t;   // slot is bucket-sorted by neighbor type
    }
    __syncthreads();

    // ---- Phase 1: per-neighbor MLP, G -> LDS --------------------------------
    if (t < K_) {
        const int k  = ksort[t];
        const int j  = k + (k >= n);
        const int ty = types[j];
        const int idx = tn * NT_ + ty;

        const float* cb = coords + (size_t)b * N_ * 3;
        const float rx = cb[n*3+0] - cb[j*3+0];
        const float ry = cb[n*3+1] - cb[j*3+1];
        const float rz = cb[n*3+2] - cb[j*3+2];
        const float d2 = rx*rx + ry*ry + rz*rz;
        const float inv_d  = rsqrtf(d2);
        const float s      = inv_d;          // 1/d
        const float inv_d2 = inv_d * inv_d;  // 1/d^2
        Al[t*3+0] = rx * inv_d2;
        Al[t*3+1] = ry * inv_d2;
        Al[t*3+2] = rz * inv_d2;

        // layer 0: 1 -> 25
        float h0[25];
        {
            const float* w0p = W0 + idx * 25;
            const float* b0p = b0 + idx * 25;
            #pragma unroll
            for (int o = 0; o < 25; ++o)
                h0[o] = fast_tanh(s * w0p[o] + b0p[o]);
        }

        // layer 1: 25 -> 50 (+ residual concat[h0,h0])
        float h1[50];
        {
            const float* b1p = b1 + idx * 50;
            #pragma unroll
            for (int o = 0; o < 50; ++o) h1[o] = b1p[o];
            const float* w1p = W1 + idx * 1250;
            #pragma unroll
            for (int i = 0; i < 25; ++i) {
                const float hi = h0[i];
                const float2* wr = (const float2*)(w1p + i * 50); // 8B aligned
                #pragma unroll
                for (int o2 = 0; o2 < 25; ++o2) {
                    float2 w = wr[o2];
                    h1[o2*2+0] += hi * w.x;
                    h1[o2*2+1] += hi * w.y;
                }
            }
            #pragma unroll
            for (int o = 0; o < 50; ++o)
                h1[o] = fast_tanh(h1[o]) + h0[o % 25];
        }

        // layer 2: 50 -> 100 (+ residual concat[h1,h1]), 5 chunks of 20
        {
            const float* w2p = W2 + idx * 5000;
            const float* b2p = b2 + idx * 100;
            #pragma unroll
            for (int c = 0; c < 5; ++c) {
                float acc[20];
                #pragma unroll
                for (int o = 0; o < 20; ++o) acc[o] = b2p[c*20+o];
                #pragma unroll
                for (int i = 0; i < 50; ++i) {
                    const float hi = h1[i];
                    const float4* wr = (const float4*)(w2p + i * 100 + c * 20); // 16B aligned
                    #pragma unroll
                    for (int o4 = 0; o4 < 5; ++o4) {
                        float4 w = wr[o4];
                        acc[o4*4+0] += hi * w.x;
                        acc[o4*4+1] += hi * w.y;
                        acc[o4*4+2] += hi * w.z;
                        acc[o4*4+3] += hi * w.w;
                    }
                }
                #pragma unroll
                for (int o = 0; o < 20; ++o) {
                    const int oo = c*20 + o;
                    G[t*101 + oo] = fast_tanh(acc[o]) + h1[oo % 50];
                }
            }
        }
    }
    __syncthreads();

    // ---- Phase 2: S[c][m] = sum_k a[k,c] * G[k,m] ---------------------------
    if (t < 300) {
        const int c = t / 100, m = t % 100;
        float S = 0.f;
        #pragma unroll 4
        for (int slot = 0; slot < K_; ++slot)
            S += Al[slot*3 + c] * G[slot*101 + m];
        Sl[t] = S;
    }
    __syncthreads();

    // ---- Phase 3: D[m][a] = sum_c S[c][m]*S[c][a] ---------------------------
    if (t < 400) {
        const int m = t >> 2, a = t & 3;
        float acc = Sl[0*100+m]*Sl[0*100+a]
                  + Sl[1*100+m]*Sl[1*100+a]
                  + Sl[2*100+m]*Sl[2*100+a];
        out[(size_t)bn * 400 + t] = acc;
    }
}

extern "C" void kernel_launch(void* const* d_in, const int* in_sizes, int n_in,
                              void* d_out, int out_size, void* d_ws, size_t ws_size,
                              hipStream_t stream) {
    const float* coords = (const float*)d_in[0];
    const int*   types  = (const int*)  d_in[1];
    const float* W0 = (const float*)d_in[2];
    const float* b0 = (const float*)d_in[3];
    const float* W1 = (const float*)d_in[4];
    const float* b1 = (const float*)d_in[5];
    const float* W2 = (const float*)d_in[6];
    const float* b2 = (const float*)d_in[7];
    float* out = (float*)d_out;

    feat_kernel<<<dim3(B_ * N_), dim3(512), 0, stream>>>(
        coords, types, W0, b0, W1, b1, W2, b2, out);
}

// Round 4
// 1166.952 us; speedup vs baseline: 1.2969x; 1.2969x over previous
//
#include <hip/hip_runtime.h>

#define B_ 8
#define N_ 384
#define K_ 383
#define NT_ 4
#define SSTR 308   // row stride for Sw; 308%32 banks -> leaders conflict-free

__device__ __forceinline__ float fast_tanh(float x) {
    // tanh(x) = 1 - 2/(exp(2x)+1); saturates correctly for |x| large.
    float e = __expf(2.0f * x);
    return 1.0f - 2.0f / (e + 1.0f);
}

__global__ __launch_bounds__(384, 4)   // force VGPR<=128 -> 16 waves/CU budget
void feat_kernel(const float* __restrict__ coords,
                 const int*   __restrict__ types,
                 const float* __restrict__ W0, const float* __restrict__ b0,
                 const float* __restrict__ W1, const float* __restrict__ b1,
                 const float* __restrict__ W2, const float* __restrict__ b2,
                 float* __restrict__ out)
{
    __shared__ float Sw[48 * SSTR];          // 59,136 B  (wave-group partial S)
    __shared__ float Sl[304];                //  1,216 B
    __shared__ unsigned short ksort[384];    //    768 B
    __shared__ int cnt[4], woff[4];          //     32 B   -> ~61 KB total

    const int t    = threadIdx.x;
    const int lane = t & 63;
    const int wv   = t >> 6;
    const int bn = blockIdx.x;
    const int b  = bn / N_;
    const int n  = bn % N_;
    const int tn = types[n];

    // ---- bucket-sort neighbors by type (wave-uniform weight reads) ----------
    if (t < 4) cnt[t] = 0;
    __syncthreads();
    int myty = 0;
    if (t < K_) {
        int jj = t + (t >= n);
        myty = types[jj];
        atomicAdd(&cnt[myty], 1);
    }
    __syncthreads();
    if (t == 0) {
        int r = 0;
        for (int q = 0; q < 4; ++q) { woff[q] = r; r += cnt[q]; }
    }
    __syncthreads();
    if (t < K_) {
        int slot = atomicAdd(&woff[myty], 1);
        ksort[slot] = (unsigned short)t;
    }
    __syncthreads();

    // ---- per-thread neighbor setup ------------------------------------------
    const bool active = (t < K_);
    int k = active ? (int)ksort[t] : 0;
    int j = k + (k >= n);
    if (!active) j = (n == 0) ? 1 : 0;      // any valid index != n
    const int ty  = types[j];
    const int idx = tn * NT_ + ty;

    const float* cb = coords + (size_t)b * N_ * 3;
    const float rx = cb[n*3+0] - cb[j*3+0];
    const float ry = cb[n*3+1] - cb[j*3+1];
    const float rz = cb[n*3+2] - cb[j*3+2];
    const float d2 = rx*rx + ry*ry + rz*rz;
    const float inv_d  = active ? rsqrtf(d2) : 1.0f;
    const float s      = inv_d;
    const float inv_d2 = inv_d * inv_d;
    const float a0 = active ? rx * inv_d2 : 0.0f;
    const float a1 = active ? ry * inv_d2 : 0.0f;
    const float a2 = active ? rz * inv_d2 : 0.0f;

    // ---- layer 0: 1 -> 25 ---------------------------------------------------
    float h0[25];
    {
        const float* w0p = W0 + idx * 25;
        const float* b0p = b0 + idx * 25;
        #pragma unroll
        for (int o = 0; o < 25; ++o)
            h0[o] = fast_tanh(s * w0p[o] + b0p[o]);
    }

    // ---- layer 1: 25 -> 50 (+ residual concat[h0,h0]) -----------------------
    float h1[50];
    {
        const float* b1p = b1 + idx * 50;
        #pragma unroll
        for (int o = 0; o < 50; ++o) h1[o] = b1p[o];
        const float* w1p = W1 + idx * 1250;
        #pragma unroll 2
        for (int i = 0; i < 25; ++i) {
            const float hi = h0[i];
            const float2* wr = (const float2*)(w1p + i * 50);   // 8B aligned
            #pragma unroll
            for (int o2 = 0; o2 < 25; ++o2) {
                float2 w = wr[o2];
                h1[o2*2+0] += hi * w.x;
                h1[o2*2+1] += hi * w.y;
            }
        }
        #pragma unroll
        for (int o = 0; o < 50; ++o)
            h1[o] = fast_tanh(h1[o]) + h0[o % 25];
    }

    // ---- layer 2 (chunks of 20) fused with S-accumulation -------------------
    // S[c][m] = sum_k a[k,c]*G[k,m]; per chunk: 3-step xor butterfly over
    // 8-lane groups, 48 group leaders write partials to Sw.
    const int  row    = wv * 8 + (lane >> 3);
    const bool leader = ((lane & 7) == 0);
    const float* w2p = W2 + idx * 5000;
    const float* b2p = b2 + idx * 100;

    #pragma unroll 1
    for (int c5 = 0; c5 < 5; ++c5) {
        float g[20];
        #pragma unroll
        for (int o = 0; o < 20; ++o) g[o] = b2p[c5*20+o];
        #pragma unroll 2
        for (int i = 0; i < 50; ++i) {
            const float hi = h1[i];
            const float4* wr = (const float4*)(w2p + i * 100 + c5 * 20); // 16B aligned
            #pragma unroll
            for (int o4 = 0; o4 < 5; ++o4) {
                float4 w = wr[o4];
                g[o4*4+0] += hi * w.x;
                g[o4*4+1] += hi * w.y;
                g[o4*4+2] += hi * w.z;
                g[o4*4+3] += hi * w.w;
            }
        }
        #pragma unroll
        for (int o = 0; o < 20; ++o)
            g[o] = fast_tanh(g[o]) + h1[(c5*20+o) % 50];

        #pragma unroll
        for (int c = 0; c < 3; ++c) {
            const float ac = (c == 0) ? a0 : (c == 1) ? a1 : a2;
            float p[20];
            #pragma unroll
            for (int o = 0; o < 20; ++o) p[o] = ac * g[o];
            #pragma unroll
            for (int st = 1; st <= 4; st <<= 1) {
                #pragma unroll
                for (int o = 0; o < 20; ++o)
                    p[o] += __shfl_xor(p[o], st, 64);
            }
            if (leader) {
                float4* dst = (float4*)&Sw[row * SSTR + c * 100 + c5 * 20];
                dst[0] = make_float4(p[ 0], p[ 1], p[ 2], p[ 3]);
                dst[1] = make_float4(p[ 4], p[ 5], p[ 6], p[ 7]);
                dst[2] = make_float4(p[ 8], p[ 9], p[10], p[11]);
                dst[3] = make_float4(p[12], p[13], p[14], p[15]);
                dst[4] = make_float4(p[16], p[17], p[18], p[19]);
            }
        }
    }
    __syncthreads();

    // ---- final S reduction over 48 rows -------------------------------------
    if (t < 300) {
        float acc = 0.f;
        #pragma unroll 8
        for (int r = 0; r < 48; ++r) acc += Sw[r * SSTR + t];
        Sl[t] = acc;
    }
    __syncthreads();

    // ---- D[m][a] = sum_c S[c][m]*S[c][a]; 400 outputs, 384 threads ----------
    {
        const int m = t >> 2, a = t & 3;
        float v = Sl[0*100+m]*Sl[0*100+a]
                + Sl[1*100+m]*Sl[1*100+a]
                + Sl[2*100+m]*Sl[2*100+a];
        out[(size_t)bn * 400 + t] = v;
        if (t < 16) {
            const int m2 = 96 + (t >> 2);
            float v2 = Sl[0*100+m2]*Sl[0*100+a]
                     + Sl[1*100+m2]*Sl[1*100+a]
                     + Sl[2*100+m2]*Sl[2*100+a];
            out[(size_t)bn * 400 + 384 + t] = v2;
        }
    }
}

extern "C" void kernel_launch(void* const* d_in, const int* in_sizes, int n_in,
                              void* d_out, int out_size, void* d_ws, size_t ws_size,
                              hipStream_t stream) {
    const float* coords = (const float*)d_in[0];
    const int*   types  = (const int*)  d_in[1];
    const float* W0 = (const float*)d_in[2];
    const float* b0 = (const float*)d_in[3];
    const float* W1 = (const float*)d_in[4];
    const float* b1 = (const float*)d_in[5];
    const float* W2 = (const float*)d_in[6];
    const float* b2 = (const float*)d_in[7];
    float* out = (float*)d_out;

    feat_kernel<<<dim3(B_ * N_), dim3(384), 0, stream>>>(
        coords, types, W0, b0, W1, b1, W2, b2, out);
}

// Round 5
// 1021.547 us; speedup vs baseline: 1.4815x; 1.1423x over previous
//
#include <hip/hip_runtime.h>

#define B_ 8
#define N_ 384
#define K_ 383
#define NT_ 4
#define SROW 456   // Sw row stride (floats): 300 (tanh part) + 3*52 (residual part)
#define SRES 300   // offset of residual section within a row
#define NROW 48    // 6 waves * 8 groups of 8 lanes

__device__ __forceinline__ float fast_tanh(float x) {
    // tanh(x) = 1 - 2/(exp(2x)+1); saturates correctly for |x| large.
    float e = __expf(2.0f * x);
    return 1.0f - 2.0f / (e + 1.0f);
}

__global__ __launch_bounds__(384, 3)   // VGPR cap ~170: fits static live set, no spill
void feat_kernel(const float* __restrict__ coords,
                 const int*   __restrict__ types,
                 const float* __restrict__ W0, const float* __restrict__ b0,
                 const float* __restrict__ W1, const float* __restrict__ b1,
                 const float* __restrict__ W2, const float* __restrict__ b2,
                 float* __restrict__ out)
{
    __shared__ float Sw[NROW * SROW];        // 87,552 B  partial S (tanh + residual)
    __shared__ float Sl[304];                //  1,216 B  final S[3][100]
    __shared__ unsigned short ksort[384];    //    768 B
    __shared__ int cnt[4], woff[4];          //     32 B   -> ~89.6 KB total

    const int t  = threadIdx.x;
    const int bn = blockIdx.x;
    const int b  = bn / N_;
    const int n  = bn % N_;
    const int tn = types[n];

    // ---- bucket-sort neighbors by type (wave-uniform weight reads) ----------
    if (t < 4) cnt[t] = 0;
    __syncthreads();
    int myty = 0;
    if (t < K_) {
        int jj = t + (t >= n);
        myty = types[jj];
        atomicAdd(&cnt[myty], 1);
    }
    __syncthreads();
    if (t == 0) {
        int r = 0;
        for (int q = 0; q < 4; ++q) { woff[q] = r; r += cnt[q]; }
    }
    __syncthreads();
    if (t < K_) {
        int slot = atomicAdd(&woff[myty], 1);
        ksort[slot] = (unsigned short)t;
    }
    __syncthreads();

    // ---- per-thread neighbor setup ------------------------------------------
    const bool active = (t < K_);
    int k = active ? (int)ksort[t] : 0;
    int j = k + (k >= n);
    if (!active) j = (n == 0) ? 1 : 0;      // any valid index != n
    const int ty  = types[j];
    const int idx = tn * NT_ + ty;

    const float* cb = coords + (size_t)b * N_ * 3;
    const float rx = cb[n*3+0] - cb[j*3+0];
    const float ry = cb[n*3+1] - cb[j*3+1];
    const float rz = cb[n*3+2] - cb[j*3+2];
    const float d2 = rx*rx + ry*ry + rz*rz;
    const float inv_d  = rsqrtf(d2);
    const float s      = inv_d;
    const float inv_d2 = inv_d * inv_d;
    const float a0 = active ? rx * inv_d2 : 0.0f;   // a==0 for pad lane ->
    const float a1 = active ? ry * inv_d2 : 0.0f;   // zero contribution to S
    const float a2 = active ? rz * inv_d2 : 0.0f;

    // ---- layer 0: 1 -> 25  (all indices static) -----------------------------
    float h0[25];
    {
        const float* w0p = W0 + idx * 25;
        const float* b0p = b0 + idx * 25;
        #pragma unroll
        for (int o = 0; o < 25; ++o)
            h0[o] = fast_tanh(s * w0p[o] + b0p[o]);
    }

    // ---- layer 1: 25 -> 50, FULLY unrolled so h0[i]/h1[o] stay in VGPRs -----
    float h1[50];
    {
        const float* b1p = b1 + idx * 50;
        #pragma unroll
        for (int o = 0; o < 50; ++o) h1[o] = b1p[o];
        const float* w1p = W1 + idx * 1250;
        #pragma unroll
        for (int i = 0; i < 25; ++i) {
            const float hi = h0[i];
            const float2* wr = (const float2*)(w1p + i * 50);   // 8B aligned
            #pragma unroll
            for (int o2 = 0; o2 < 25; ++o2) {
                float2 w = wr[o2];
                h1[o2*2+0] += hi * w.x;
                h1[o2*2+1] += hi * w.y;
            }
        }
        #pragma unroll
        for (int o = 0; o < 50; ++o)
            h1[o] = fast_tanh(h1[o]) + h0[o % 25];
    }

    const int  row    = t >> 3;             // 8-lane group id, 0..47
    const bool leader = ((t & 7) == 0);

    // ---- residual part of S: Sres[c][j] = sum_k a[k,c]*h1[k,j] --------------
    // (butterfly over 8-lane groups while h1 is statically register-resident)
    #pragma unroll
    for (int c = 0; c < 3; ++c) {
        const float ac = (c == 0) ? a0 : (c == 1) ? a1 : a2;
        float p[50];
        #pragma unroll
        for (int o = 0; o < 50; ++o) p[o] = ac * h1[o];
        #pragma unroll
        for (int st = 1; st <= 4; st <<= 1) {
            #pragma unroll
            for (int o = 0; o < 50; ++o)
                p[o] += __shfl_xor(p[o], st, 64);
        }
        if (leader) {
            float* dst = &Sw[row * SROW + SRES + c * 52];       // 16B aligned
            #pragma unroll
            for (int o4 = 0; o4 < 12; ++o4)
                ((float4*)dst)[o4] = make_float4(p[o4*4+0], p[o4*4+1],
                                                 p[o4*4+2], p[o4*4+3]);
            dst[48] = p[48];
            dst[49] = p[49];
        }
    }

    // ---- layer 2 (5 chunks of 20) fused with tanh-part S-accumulation -------
    // c5 loop stays RUNTIME (small code) -- no register array is indexed by it.
    const float* w2base = W2 + idx * 5000;
    const float* b2p    = b2 + idx * 100;
    #pragma unroll 1
    for (int c5 = 0; c5 < 5; ++c5) {
        float g[20];
        const float* bb = b2p + c5 * 20;
        #pragma unroll
        for (int o = 0; o < 20; ++o) g[o] = bb[o];
        const float* w2p = w2base + c5 * 20;
        #pragma unroll
        for (int i = 0; i < 50; ++i) {                  // FULL unroll: h1[i] static
            const float hi = h1[i];
            const float4* wr = (const float4*)(w2p + i * 100);  // 16B aligned
            #pragma unroll
            for (int o4 = 0; o4 < 5; ++o4) {
                float4 w = wr[o4];
                g[o4*4+0] += hi * w.x;
                g[o4*4+1] += hi * w.y;
                g[o4*4+2] += hi * w.z;
                g[o4*4+3] += hi * w.w;
            }
        }
        #pragma unroll
        for (int o = 0; o < 20; ++o) g[o] = fast_tanh(g[o]);    // residual handled via Sres

        #pragma unroll
        for (int c = 0; c < 3; ++c) {
            const float ac = (c == 0) ? a0 : (c == 1) ? a1 : a2;
            float p[20];
            #pragma unroll
            for (int o = 0; o < 20; ++o) p[o] = ac * g[o];
            #pragma unroll
            for (int st = 1; st <= 4; st <<= 1) {
                #pragma unroll
                for (int o = 0; o < 20; ++o)
                    p[o] += __shfl_xor(p[o], st, 64);
            }
            if (leader) {
                float* dst = &Sw[row * SROW + c * 100 + c5 * 20];  // 16B aligned
                #pragma unroll
                for (int o4 = 0; o4 < 5; ++o4)
                    ((float4*)dst)[o4] = make_float4(p[o4*4+0], p[o4*4+1],
                                                     p[o4*4+2], p[o4*4+3]);
            }
        }
    }
    __syncthreads();

    // ---- final S reduction over 48 group rows (tanh part + residual part) ---
    if (t < 300) {
        const int c = t / 100;
        const int m = t - c * 100;
        const int jr = (m >= 50) ? m - 50 : m;
        float acc = 0.f;
        #pragma unroll 6
        for (int r = 0; r < NROW; ++r)
            acc += Sw[r * SROW + t] + Sw[r * SROW + SRES + c * 52 + jr];
        Sl[t] = acc;
    }
    __syncthreads();

    // ---- D[m][a] = sum_c S[c][m]*S[c][a]; 400 outputs, 384 threads ----------
    {
        const int m = t >> 2, a = t & 3;
        float v = Sl[0*100+m]*Sl[0*100+a]
                + Sl[1*100+m]*Sl[1*100+a]
                + Sl[2*100+m]*Sl[2*100+a];
        out[(size_t)bn * 400 + t] = v;
        if (t < 16) {
            const int m2 = 96 + (t >> 2);
            float v2 = Sl[0*100+m2]*Sl[0*100+a]
                     + Sl[1*100+m2]*Sl[1*100+a]
                     + Sl[2*100+m2]*Sl[2*100+a];
            out[(size_t)bn * 400 + 384 + t] = v2;
        }
    }
}

extern "C" void kernel_launch(void* const* d_in, const int* in_sizes, int n_in,
                              void* d_out, int out_size, void* d_ws, size_t ws_size,
                              hipStream_t stream) {
    const float* coords = (const float*)d_in[0];
    const int*   types  = (const int*)  d_in[1];
    const float* W0 = (const float*)d_in[2];
    const float* b0 = (const float*)d_in[3];
    const float* W1 = (const float*)d_in[4];
    const float* b1 = (const float*)d_in[5];
    const float* W2 = (const float*)d_in[6];
    const float* b2 = (const float*)d_in[7];
    float* out = (float*)d_out;

    feat_kernel<<<dim3(B_ * N_), dim3(384), 0, stream>>>(
        coords, types, W0, b0, W1, b1, W2, b2, out);
}